// Round 14
// baseline (512.361 us; speedup 1.0000x reference)
//
#include <hip/hip_runtime.h>
#include <stdint.h>

#define NM 128   // matrix dim / electrons
#define NT 256   // 4 waves; wave w owns cols [32w..32w+31]; lane l owns rows l, l+64
                 // sv[j] = (S[l][32w+j], S[l+64][32w+j]) — 64 VGPRs of state

typedef float v2f __attribute__((ext_vector_type(2)));

__device__ __forceinline__ float readlane_f(float v, int lane) {
    return __int_as_float(__builtin_amdgcn_readlane(__float_as_int(v), lane));
}

// Full 64-lane unsigned max via DPP (VALU pipe); result valid in lane 63.
__device__ __forceinline__ unsigned wave_max_dpp(unsigned x) {
    int v = (int)x;
#define DPP_STEP(ctrl) \
    { int o = __builtin_amdgcn_update_dpp(0, v, ctrl, 0xf, 0xf, true); \
      v = ((unsigned)o > (unsigned)v) ? o : v; }
    DPP_STEP(0x111)  // row_shr:1
    DPP_STEP(0x112)  // row_shr:2
    DPP_STEP(0x114)  // row_shr:4
    DPP_STEP(0x118)  // row_shr:8
    DPP_STEP(0x142)  // row_bcast:15
    DPP_STEP(0x143)  // row_bcast:31
#undef DPP_STEP
    return (unsigned)v;
}

__device__ __forceinline__ unsigned pack_key(float v, int r) {
    // monotone in |v|; drop 6 mantissa LSBs to make room for the 7-bit row id
    return (((__float_as_uint(v) & 0x7fffffffu) >> 6) << 7) | (unsigned)r;
}

// max(ka,kb) over the wave, broadcast to all lanes (uniform result)
__device__ __forceinline__ unsigned argmax_bcast(unsigned ka, unsigned kb) {
    const unsigned m = wave_max_dpp(ka > kb ? ka : kb);
    return (unsigned)__builtin_amdgcn_readlane((int)m, 63);
}

// read pivot row p's element of a (row r0, row r1) register pair; p uniform
__device__ __forceinline__ float sel_readlane(v2f c, int p) {
    return (p < 64) ? readlane_f(c.x, p) : readlane_f(c.y, p - 64);
}

// one elimination step on cols [B, B+8): batch 8 readlanes then 8 pk_fma
template<int B>
__device__ __forceinline__ void extract_apply8(v2f (&sv)[32], int p, v2f lm) {
    float u[8];
    if (p < 64) {
#pragma unroll
        for (int j = 0; j < 8; ++j) u[j] = readlane_f(sv[B + j].x, p);
    } else {
#pragma unroll
        for (int j = 0; j < 8; ++j) u[j] = readlane_f(sv[B + j].y, p - 64);
    }
#pragma unroll
    for (int j = 0; j < 8; ++j)
        sv[B + j] = __builtin_elementwise_fma((v2f){-u[j], -u[j]}, lm, sv[B + j]);
}

// apply the round's 8 steps (in order) to col blocks [B0*8, 32)
template<int B0>
__device__ __forceinline__ void applyFrom(v2f (&sv)[32], const int (&p)[8],
                                          const v2f (&lm)[8]) {
#pragma unroll
    for (int i = 0; i < 8; ++i) {
        if (B0 <= 0) extract_apply8<0 >(sv, p[i], lm[i]);
        if (B0 <= 1) extract_apply8<8 >(sv, p[i], lm[i]);
        if (B0 <= 2) extract_apply8<16>(sv, p[i], lm[i]);
        if (B0 <= 3) extract_apply8<24>(sv, p[i], lm[i]);
    }
}

// factor 8 cols sv[B..B+7] in place (they die afterwards), publishing
// pre-multiplied+pre-zeroed multipliers, keys, exact pivots, elim ballots.
template<int B>
__device__ __forceinline__ void lookahead8(v2f (&sv)[32], bool& elim0, bool& elim1,
                                           int r0, int r1, int l, int g,
                                           float2 (*colvg)[64],
                                           unsigned* keysF, float* pivsF,
                                           ulonglong2* masks) {
    const bool e0in = elim0, e1in = elim1;
#pragma unroll
    for (int i = 0; i < 8; ++i) {
        const v2f c = sv[B + i];
        const unsigned key = argmax_bcast(elim0 ? 0u : pack_key(c.x, r0),
                                          elim1 ? 0u : pack_key(c.y, r1));
        const int pu = __builtin_amdgcn_readfirstlane((int)(key & 127u));
        const float piv = sel_readlane(c, pu);
        const float rcp = __builtin_amdgcn_rcpf(piv);
        elim0 = elim0 || (r0 == pu);
        elim1 = elim1 || (r1 == pu);
        const v2f lm = { elim0 ? 0.0f : c.x * rcp,
                         elim1 ? 0.0f : c.y * rcp };
        colvg[i][l] = make_float2(lm.x, lm.y);
#pragma unroll
        for (int m = i + 1; m < 8; ++m) {
            const float u = sel_readlane(sv[B + m], pu);
            sv[B + m] = __builtin_elementwise_fma((v2f){-u, -u}, lm, sv[B + m]);
        }
        if (l == 0) { keysF[8 * g + i] = key; pivsF[8 * g + i] = piv; }
    }
    const unsigned long long b0 = __ballot(elim0 && !e0in);
    const unsigned long long b1 = __ballot(elim1 && !e1in);
    if (l == 0) masks[g] = make_ulonglong2(b0, b1);
}

__global__ __launch_bounds__(NT, 4)   // VGPR cap 128: fits sv[32]+temps (~100)
void slater_logdet(const float* __restrict__ rs,
                   const float* __restrict__ kpts,
                   const float* __restrict__ csw,
                   const float* __restrict__ ssw,
                   float* __restrict__ out) {
    __shared__ float2 colv[2][8][64];      // pre-multiplied, pre-zeroed pairs
    __shared__ unsigned keysF[NM];         // write-once pivot keys per step
    __shared__ float    pivsF[NM];         // write-once exact pivots
    __shared__ ulonglong2 masks[NM / 8];   // per-group new-pivot row ballots
    __shared__ float    redf[2];

    const int t  = threadIdx.x;
    const int b  = blockIdx.x;
    const int w  = t >> 6;    // wave id; owns groups 4w..4w+3
    const int l  = t & 63;
    const int c0 = w << 5;
    const int r0 = l, r1 = l + 64;

    v2f sv[32];   // sv[j] = (row r0, row r1) at col c0+j
    {
        const float x0 = rs[(b * NM + r0) * 3 + 0];
        const float y0 = rs[(b * NM + r0) * 3 + 1];
        const float z0 = rs[(b * NM + r0) * 3 + 2];
        const float x1 = rs[(b * NM + r1) * 3 + 0];
        const float y1 = rs[(b * NM + r1) * 3 + 1];
        const float z1 = rs[(b * NM + r1) * 3 + 2];
#pragma unroll
        for (int j = 0; j < 32; ++j) {
            const int m = c0 + j;  // wave-uniform -> scalar loads
            const float kx = kpts[m * 3 + 0], ky = kpts[m * 3 + 1], kz = kpts[m * 3 + 2];
            const float cw = csw[m], sw = ssw[m];
            float sn, cn;
            __sincosf(kx * x0 + ky * y0 + kz * z0, &sn, &cn);
            sv[j].x = cw * cn - sw * sn;
            __sincosf(kx * x1 + ky * y1 + kz * z1, &sn, &cn);
            sv[j].y = cw * cn - sw * sn;
        }
    }

    bool elim0 = false, elim1 = false;

    // ---- bootstrap: wave 0 factors & publishes group 0 (its cols 0-7) ----
    if (w == 0)
        lookahead8<0>(sv, elim0, elim1, r0, r1, l, 0, colv[0], keysF, pivsF, masks);
    __syncthreads();

    // ---- main loop: 15 rounds; round rd applies group rd.
    // Wave w: d = rd - (4w - 1):
    //   d < 0 : full 32-col apply (consumer)
    //   d == 0: full apply + lookahead cols 0-7   (group 4w)
    //   d == 1: apply cols 8-31  + lookahead 8-15 (group 4w+1)
    //   d == 2: apply cols 16-31 + lookahead 16-23(group 4w+2)
    //   d == 3: apply cols 24-31 + lookahead 24-31(group 4w+3); retire.
    const int base    = 4 * w - 1;
    const int liveEnd = (4 * w + 2 < 14) ? 4 * w + 2 : 14;
    int rd = 0;
    for (; rd <= liveEnd; ++rd) {
        const uint4 ka = *(const uint4*)&keysF[8 * rd];
        const uint4 kb = *(const uint4*)&keysF[8 * rd + 4];
        int p[8];
        p[0] = __builtin_amdgcn_readfirstlane((int)(ka.x & 127u));
        p[1] = __builtin_amdgcn_readfirstlane((int)(ka.y & 127u));
        p[2] = __builtin_amdgcn_readfirstlane((int)(ka.z & 127u));
        p[3] = __builtin_amdgcn_readfirstlane((int)(ka.w & 127u));
        p[4] = __builtin_amdgcn_readfirstlane((int)(kb.x & 127u));
        p[5] = __builtin_amdgcn_readfirstlane((int)(kb.y & 127u));
        p[6] = __builtin_amdgcn_readfirstlane((int)(kb.z & 127u));
        p[7] = __builtin_amdgcn_readfirstlane((int)(kb.w & 127u));
        const ulonglong2 mk = masks[rd];
        elim0 = elim0 || (((mk.x >> l) & 1ull) != 0);
        elim1 = elim1 || (((mk.y >> l) & 1ull) != 0);

        const int par = rd & 1;
        v2f lm[8];
#pragma unroll
        for (int i = 0; i < 8; ++i) {
            const float2 la = colv[par][i][l];
            lm[i] = (v2f){la.x, la.y};
        }

        const int d = rd - base;   // wave-uniform
        if (d < 0) {
            applyFrom<0>(sv, p, lm);
        } else if (d == 0) {
            applyFrom<0>(sv, p, lm);
            lookahead8<0 >(sv, elim0, elim1, r0, r1, l, rd + 1,
                           colv[(rd + 1) & 1], keysF, pivsF, masks);
        } else if (d == 1) {
            applyFrom<1>(sv, p, lm);
            lookahead8<8 >(sv, elim0, elim1, r0, r1, l, rd + 1,
                           colv[(rd + 1) & 1], keysF, pivsF, masks);
        } else if (d == 2) {
            applyFrom<2>(sv, p, lm);
            lookahead8<16>(sv, elim0, elim1, r0, r1, l, rd + 1,
                           colv[(rd + 1) & 1], keysF, pivsF, masks);
        } else {  // d == 3
            applyFrom<3>(sv, p, lm);
            if (rd + 1 < 16)
                lookahead8<24>(sv, elim0, elim1, r0, r1, l, rd + 1,
                               colv[(rd + 1) & 1], keysF, pivsF, masks);
        }
        __syncthreads();
    }
    for (; rd < 15; ++rd) __syncthreads();   // retired waves: barrier-only

    // ---- log|det| = sum log|piv_k| over the write-once pivsF array ----
    float lg = 0.0f;
    if (t < NM) {
        lg = __logf(fabsf(pivsF[t]));
#pragma unroll
        for (int off = 32; off > 0; off >>= 1)
            lg += __shfl_xor(lg, off, 64);
        if ((t & 63) == 0) redf[t >> 6] = lg;
    }
    __syncthreads();
    if (t == 0) out[b] = redf[0] + redf[1];
}

extern "C" void kernel_launch(void* const* d_in, const int* in_sizes, int n_in,
                              void* d_out, int out_size, void* d_ws, size_t ws_size,
                              hipStream_t stream) {
    const float* rs = (const float*)d_in[0];
    const float* kp = (const float*)d_in[1];
    const float* cs = (const float*)d_in[2];
    const float* ss = (const float*)d_in[3];
    float* out = (float*)d_out;
    const int batch = in_sizes[0] / (NM * 3);  // 4096
    slater_logdet<<<dim3(batch), dim3(NT), 0, stream>>>(rs, kp, cs, ss, out);
}

// Round 15
// 372.115 us; speedup vs baseline: 1.3769x; 1.3769x over previous
//
#include <hip/hip_runtime.h>
#include <stdint.h>

#define NM 128   // matrix dim / electrons
#define NT 512   // 8 waves; wave w owns cols [16w..16w+15]; lane l owns rows l, l+64
                 // sv[j] = (S[l][16w+j], S[l+64][16w+j]) — 32 VGPRs of state

typedef float v2f __attribute__((ext_vector_type(2)));

__device__ __forceinline__ float readlane_f(float v, int lane) {
    return __int_as_float(__builtin_amdgcn_readlane(__float_as_int(v), lane));
}

// Full 64-lane unsigned max via DPP (VALU pipe); result valid in lane 63.
__device__ __forceinline__ unsigned wave_max_dpp(unsigned x) {
    int v = (int)x;
#define DPP_STEP(ctrl) \
    { int o = __builtin_amdgcn_update_dpp(0, v, ctrl, 0xf, 0xf, true); \
      v = ((unsigned)o > (unsigned)v) ? o : v; }
    DPP_STEP(0x111)  // row_shr:1
    DPP_STEP(0x112)  // row_shr:2
    DPP_STEP(0x114)  // row_shr:4
    DPP_STEP(0x118)  // row_shr:8
    DPP_STEP(0x142)  // row_bcast:15
    DPP_STEP(0x143)  // row_bcast:31
#undef DPP_STEP
    return (unsigned)v;
}

__device__ __forceinline__ unsigned pack_key(float v, int r) {
    // monotone in |v|; drop 6 mantissa LSBs to make room for the 7-bit row id
    return (((__float_as_uint(v) & 0x7fffffffu) >> 6) << 7) | (unsigned)r;
}

// max(ka,kb) over the wave, broadcast to all lanes (uniform result)
__device__ __forceinline__ unsigned argmax_bcast(unsigned ka, unsigned kb) {
    const unsigned m = wave_max_dpp(ka > kb ? ka : kb);
    return (unsigned)__builtin_amdgcn_readlane((int)m, 63);
}

// read pivot row p's element of a (row r0, row r1) register pair; p uniform
__device__ __forceinline__ float sel_readlane(v2f c, int p) {
    return (p < 64) ? readlane_f(c.x, p) : readlane_f(c.y, p - 64);
}

// one elimination step on cols [B, B+8): batch 8 readlanes then 8 pk_fma
template<int B>
__device__ __forceinline__ void extract_apply8(v2f (&sv)[16], int p, v2f lm) {
    float u[8];
    if (p < 64) {
#pragma unroll
        for (int j = 0; j < 8; ++j) u[j] = readlane_f(sv[B + j].x, p);
    } else {
#pragma unroll
        for (int j = 0; j < 8; ++j) u[j] = readlane_f(sv[B + j].y, p - 64);
    }
#pragma unroll
    for (int j = 0; j < 8; ++j)
        sv[B + j] = __builtin_elementwise_fma((v2f){-u[j], -u[j]}, lm, sv[B + j]);
}

// factor 8 cols sv[B..B+7] in place (they die afterwards), publishing
// pre-multiplied+pre-zeroed multipliers, keys, exact pivots, elim ballots.
template<int B>
__device__ __forceinline__ void lookahead8(v2f (&sv)[16], bool& elim0, bool& elim1,
                                           int r0, int r1, int l, int g,
                                           float2 (*colvg)[64],
                                           unsigned* keysF, float* pivsF,
                                           ulonglong2* masks) {
    const bool e0in = elim0, e1in = elim1;
#pragma unroll
    for (int i = 0; i < 8; ++i) {
        const v2f c = sv[B + i];
        const unsigned key = argmax_bcast(elim0 ? 0u : pack_key(c.x, r0),
                                          elim1 ? 0u : pack_key(c.y, r1));
        const int pu = __builtin_amdgcn_readfirstlane((int)(key & 127u));
        const float piv = sel_readlane(c, pu);
        const float rcp = __builtin_amdgcn_rcpf(piv);
        elim0 = elim0 || (r0 == pu);
        elim1 = elim1 || (r1 == pu);
        const v2f lm = { elim0 ? 0.0f : c.x * rcp,
                         elim1 ? 0.0f : c.y * rcp };
        colvg[i][l] = make_float2(lm.x, lm.y);
#pragma unroll
        for (int m = i + 1; m < 8; ++m) {
            const float u = sel_readlane(sv[B + m], pu);
            sv[B + m] = __builtin_elementwise_fma((v2f){-u, -u}, lm, sv[B + m]);
        }
        if (l == 0) { keysF[8 * g + i] = key; pivsF[8 * g + i] = piv; }
    }
    const unsigned long long b0 = __ballot(elim0 && !e0in);
    const unsigned long long b1 = __ballot(elim1 && !e1in);
    if (l == 0) masks[g] = make_ulonglong2(b0, b1);
}

__global__ __launch_bounds__(NT, 8)   // 8 waves/EU = 4 blocks/CU; VGPR cap 64 (meas. demand 40)
void slater_logdet(const float* __restrict__ rs,
                   const float* __restrict__ kpts,
                   const float* __restrict__ csw,
                   const float* __restrict__ ssw,
                   float* __restrict__ out) {
    __shared__ float2 colv[2][8][64];      // pre-multiplied, pre-zeroed pairs
    __shared__ unsigned keysF[NM];         // write-once pivot keys per step
    __shared__ float    pivsF[NM];         // write-once exact pivots
    __shared__ ulonglong2 masks[NM / 8];   // per-group new-pivot row ballots
    __shared__ float    redf[2];

    const int t  = threadIdx.x;
    const int b  = blockIdx.x;
    const int w  = t >> 6;    // wave id = 16-col slab id (groups 2w, 2w+1)
    const int l  = t & 63;
    const int c0 = w << 4;
    const int r0 = l, r1 = l + 64;

    v2f sv[16];   // sv[j] = (row r0, row r1) at col c0+j
    {
        const float x0 = rs[(b * NM + r0) * 3 + 0];
        const float y0 = rs[(b * NM + r0) * 3 + 1];
        const float z0 = rs[(b * NM + r0) * 3 + 2];
        const float x1 = rs[(b * NM + r1) * 3 + 0];
        const float y1 = rs[(b * NM + r1) * 3 + 1];
        const float z1 = rs[(b * NM + r1) * 3 + 2];
#pragma unroll
        for (int j = 0; j < 16; ++j) {
            const int m = c0 + j;  // wave-uniform -> scalar loads
            const float kx = kpts[m * 3 + 0], ky = kpts[m * 3 + 1], kz = kpts[m * 3 + 2];
            const float cw = csw[m], sw = ssw[m];
            float sn, cn;
            __sincosf(kx * x0 + ky * y0 + kz * z0, &sn, &cn);
            sv[j].x = cw * cn - sw * sn;
            __sincosf(kx * x1 + ky * y1 + kz * z1, &sn, &cn);
            sv[j].y = cw * cn - sw * sn;
        }
    }

    bool elim0 = false, elim1 = false;

    // ---- bootstrap: wave 0 factors & publishes group 0 (its cols 0-7) ----
    if (w == 0)
        lookahead8<0>(sv, elim0, elim1, r0, r1, l, 0, colv[0], keysF, pivsF, masks);
    __syncthreads();

    // ---- main loop: 15 rounds; round rd applies group rd.
    // Wave w: consumer (full 16-col apply) for rd < 2w-1;
    //   rd == 2w-1: full apply + lookahead on cols 0-7  (group 2w);
    //   rd == 2w  : high-half apply + lookahead on cols 8-15 (group 2w+1); retire.
    const int liveEnd = (2 * w < 14) ? 2 * w : 14;
    int rd = 0;
    for (; rd <= liveEnd; ++rd) {
        const uint4 ka = *(const uint4*)&keysF[8 * rd];
        const uint4 kb = *(const uint4*)&keysF[8 * rd + 4];
        int p[8];
        p[0] = __builtin_amdgcn_readfirstlane((int)(ka.x & 127u));
        p[1] = __builtin_amdgcn_readfirstlane((int)(ka.y & 127u));
        p[2] = __builtin_amdgcn_readfirstlane((int)(ka.z & 127u));
        p[3] = __builtin_amdgcn_readfirstlane((int)(ka.w & 127u));
        p[4] = __builtin_amdgcn_readfirstlane((int)(kb.x & 127u));
        p[5] = __builtin_amdgcn_readfirstlane((int)(kb.y & 127u));
        p[6] = __builtin_amdgcn_readfirstlane((int)(kb.z & 127u));
        p[7] = __builtin_amdgcn_readfirstlane((int)(kb.w & 127u));
        const ulonglong2 mk = masks[rd];
        elim0 = elim0 || (((mk.x >> l) & 1ull) != 0);
        elim1 = elim1 || (((mk.y >> l) & 1ull) != 0);

        const int par = rd & 1;
        if (rd < 2 * w) {   // full 16-col apply; load lm just-in-time (low pressure)
#pragma unroll
            for (int i = 0; i < 8; ++i) {
                const float2 la = colv[par][i][l];
                const v2f lm = (v2f){la.x, la.y};
                extract_apply8<0>(sv, p[i], lm);
                extract_apply8<8>(sv, p[i], lm);
            }
        } else {            // rd == 2w: cols 0-7 already factored, apply high half
#pragma unroll
            for (int i = 0; i < 8; ++i) {
                const float2 la = colv[par][i][l];
                extract_apply8<8>(sv, p[i], (v2f){la.x, la.y});
            }
        }

        if (rd == 2 * w - 1)
            lookahead8<0>(sv, elim0, elim1, r0, r1, l, rd + 1,
                          colv[(rd + 1) & 1], keysF, pivsF, masks);
        if (rd == 2 * w)
            lookahead8<8>(sv, elim0, elim1, r0, r1, l, rd + 1,
                          colv[(rd + 1) & 1], keysF, pivsF, masks);

        __syncthreads();
    }
    for (; rd < 15; ++rd) __syncthreads();   // retired waves: barrier-only

    // ---- log|det| = sum log|piv_k| over the write-once pivsF array ----
    float lg = 0.0f;
    if (t < NM) {
        lg = __logf(fabsf(pivsF[t]));
#pragma unroll
        for (int off = 32; off > 0; off >>= 1)
            lg += __shfl_xor(lg, off, 64);
        if ((t & 63) == 0) redf[t >> 6] = lg;
    }
    __syncthreads();
    if (t == 0) out[b] = redf[0] + redf[1];
}

extern "C" void kernel_launch(void* const* d_in, const int* in_sizes, int n_in,
                              void* d_out, int out_size, void* d_ws, size_t ws_size,
                              hipStream_t stream) {
    const float* rs = (const float*)d_in[0];
    const float* kp = (const float*)d_in[1];
    const float* cs = (const float*)d_in[2];
    const float* ss = (const float*)d_in[3];
    float* out = (float*)d_out;
    const int batch = in_sizes[0] / (NM * 3);  // 4096
    slater_logdet<<<dim3(batch), dim3(NT), 0, stream>>>(rs, kp, cs, ss, out);
}

// Round 16
// 369.948 us; speedup vs baseline: 1.3850x; 1.0059x over previous
//
#include <hip/hip_runtime.h>
#include <stdint.h>

#define NM 128   // matrix dim / electrons
#define NT 512   // 8 waves; CYCLIC ownership: wave w owns group w (cols 8w..8w+7)
                 // in sv[0..7] and group w+8 (cols 64+8w..64+8w+7) in sv[8..15].
                 // lane l owns rows l, l+64.

typedef float v2f __attribute__((ext_vector_type(2)));

__device__ __forceinline__ float readlane_f(float v, int lane) {
    return __int_as_float(__builtin_amdgcn_readlane(__float_as_int(v), lane));
}

// Full 64-lane unsigned max via DPP (VALU pipe); result valid in lane 63.
__device__ __forceinline__ unsigned wave_max_dpp(unsigned x) {
    int v = (int)x;
#define DPP_STEP(ctrl) \
    { int o = __builtin_amdgcn_update_dpp(0, v, ctrl, 0xf, 0xf, true); \
      v = ((unsigned)o > (unsigned)v) ? o : v; }
    DPP_STEP(0x111)  // row_shr:1
    DPP_STEP(0x112)  // row_shr:2
    DPP_STEP(0x114)  // row_shr:4
    DPP_STEP(0x118)  // row_shr:8
    DPP_STEP(0x142)  // row_bcast:15
    DPP_STEP(0x143)  // row_bcast:31
#undef DPP_STEP
    return (unsigned)v;
}

__device__ __forceinline__ unsigned pack_key(float v, int r) {
    // monotone in |v|; drop 6 mantissa LSBs to make room for the 7-bit row id
    return (((__float_as_uint(v) & 0x7fffffffu) >> 6) << 7) | (unsigned)r;
}

// max(ka,kb) over the wave, broadcast to all lanes (uniform result)
__device__ __forceinline__ unsigned argmax_bcast(unsigned ka, unsigned kb) {
    const unsigned m = wave_max_dpp(ka > kb ? ka : kb);
    return (unsigned)__builtin_amdgcn_readlane((int)m, 63);
}

// read pivot row p's element of a (row r0, row r1) register pair; p uniform
__device__ __forceinline__ float sel_readlane(v2f c, int p) {
    return (p < 64) ? readlane_f(c.x, p) : readlane_f(c.y, p - 64);
}

// one elimination step on cols [B, B+8): batch 8 readlanes then 8 pk_fma
template<int B>
__device__ __forceinline__ void extract_apply8(v2f (&sv)[16], int p, v2f lm) {
    float u[8];
    if (p < 64) {
#pragma unroll
        for (int j = 0; j < 8; ++j) u[j] = readlane_f(sv[B + j].x, p);
    } else {
#pragma unroll
        for (int j = 0; j < 8; ++j) u[j] = readlane_f(sv[B + j].y, p - 64);
    }
#pragma unroll
    for (int j = 0; j < 8; ++j)
        sv[B + j] = __builtin_elementwise_fma((v2f){-u[j], -u[j]}, lm, sv[B + j]);
}

// factor 8 cols sv[B..B+7] in place (they die afterwards), publishing
// pre-multiplied+pre-zeroed multipliers, keys, exact pivots, elim ballots.
template<int B>
__device__ __forceinline__ void lookahead8(v2f (&sv)[16], bool& elim0, bool& elim1,
                                           int r0, int r1, int l, int g,
                                           float2 (*colvg)[64],
                                           unsigned* keysF, float* pivsF,
                                           ulonglong2* masks) {
    const bool e0in = elim0, e1in = elim1;
#pragma unroll
    for (int i = 0; i < 8; ++i) {
        const v2f c = sv[B + i];
        const unsigned key = argmax_bcast(elim0 ? 0u : pack_key(c.x, r0),
                                          elim1 ? 0u : pack_key(c.y, r1));
        const int pu = __builtin_amdgcn_readfirstlane((int)(key & 127u));
        const float piv = sel_readlane(c, pu);
        const float rcp = __builtin_amdgcn_rcpf(piv);
        elim0 = elim0 || (r0 == pu);
        elim1 = elim1 || (r1 == pu);
        const v2f lm = { elim0 ? 0.0f : c.x * rcp,
                         elim1 ? 0.0f : c.y * rcp };
        colvg[i][l] = make_float2(lm.x, lm.y);
#pragma unroll
        for (int m = i + 1; m < 8; ++m) {
            const float u = sel_readlane(sv[B + m], pu);
            sv[B + m] = __builtin_elementwise_fma((v2f){-u, -u}, lm, sv[B + m]);
        }
        if (l == 0) { keysF[8 * g + i] = key; pivsF[8 * g + i] = piv; }
    }
    const unsigned long long b0 = __ballot(elim0 && !e0in);
    const unsigned long long b1 = __ballot(elim1 && !e1in);
    if (l == 0) masks[g] = make_ulonglong2(b0, b1);
}

__global__ __launch_bounds__(NT, 8)   // 8 waves/EU = 4 blocks/CU (R15: wins over clean 3)
void slater_logdet(const float* __restrict__ rs,
                   const float* __restrict__ kpts,
                   const float* __restrict__ csw,
                   const float* __restrict__ ssw,
                   float* __restrict__ out) {
    __shared__ float2 colv[2][8][64];      // pre-multiplied, pre-zeroed pairs
    __shared__ unsigned keysF[NM];         // write-once pivot keys per step
    __shared__ float    pivsF[NM];         // write-once exact pivots
    __shared__ ulonglong2 masks[NM / 8];   // per-group new-pivot row ballots
    __shared__ float    redf[2];

    const int t  = threadIdx.x;
    const int b  = blockIdx.x;
    const int w  = t >> 6;    // wave id; owns groups w and w+8
    const int l  = t & 63;
    const int r0 = l, r1 = l + 64;

    v2f sv[16];   // sv[j<8] = (rows r0,r1) at col 8w+j ; sv[j>=8] = col 64+8w+(j-8)
    {
        const float x0 = rs[(b * NM + r0) * 3 + 0];
        const float y0 = rs[(b * NM + r0) * 3 + 1];
        const float z0 = rs[(b * NM + r0) * 3 + 2];
        const float x1 = rs[(b * NM + r1) * 3 + 0];
        const float y1 = rs[(b * NM + r1) * 3 + 1];
        const float z1 = rs[(b * NM + r1) * 3 + 2];
#pragma unroll
        for (int j = 0; j < 16; ++j) {
            const int m = (j < 8) ? (8 * w + j) : (64 + 8 * w + (j - 8));
            const float kx = kpts[m * 3 + 0], ky = kpts[m * 3 + 1], kz = kpts[m * 3 + 2];
            const float cw = csw[m], sw = ssw[m];
            float sn, cn;
            __sincosf(kx * x0 + ky * y0 + kz * z0, &sn, &cn);
            sv[j].x = cw * cn - sw * sn;
            __sincosf(kx * x1 + ky * y1 + kz * z1, &sn, &cn);
            sv[j].y = cw * cn - sw * sn;
        }
    }

    bool elim0 = false, elim1 = false;

    // ---- bootstrap: wave 0 factors & publishes group 0 (its chunk A) ----
    if (w == 0)
        lookahead8<0>(sv, elim0, elim1, r0, r1, l, 0, colv[0], keysF, pivsF, masks);
    __syncthreads();

    // ---- main loop: 15 rounds; round rd applies group rd.
    // Wave w: chunk A (sv[0..7], group w) is applied for rd < w, factored
    //   during round w-1 (lookahead). Chunk B (sv[8..15], group w+8) is applied
    //   for all rd <= w+7, factored during round w+7. Wave idles after w+7.
    const int liveEnd = w + 7;
    int rd = 0;
    for (; rd <= liveEnd; ++rd) {
        const uint4 ka = *(const uint4*)&keysF[8 * rd];
        const uint4 kb = *(const uint4*)&keysF[8 * rd + 4];
        int p[8];
        p[0] = __builtin_amdgcn_readfirstlane((int)(ka.x & 127u));
        p[1] = __builtin_amdgcn_readfirstlane((int)(ka.y & 127u));
        p[2] = __builtin_amdgcn_readfirstlane((int)(ka.z & 127u));
        p[3] = __builtin_amdgcn_readfirstlane((int)(ka.w & 127u));
        p[4] = __builtin_amdgcn_readfirstlane((int)(kb.x & 127u));
        p[5] = __builtin_amdgcn_readfirstlane((int)(kb.y & 127u));
        p[6] = __builtin_amdgcn_readfirstlane((int)(kb.z & 127u));
        p[7] = __builtin_amdgcn_readfirstlane((int)(kb.w & 127u));
        const ulonglong2 mk = masks[rd];
        elim0 = elim0 || (((mk.x >> l) & 1ull) != 0);
        elim1 = elim1 || (((mk.y >> l) & 1ull) != 0);

        const int par = rd & 1;
        if (rd < w) {       // both chunks live: 16-col apply, JIT lm loads
#pragma unroll
            for (int i = 0; i < 8; ++i) {
                const float2 la = colv[par][i][l];
                const v2f lm = (v2f){la.x, la.y};
                extract_apply8<0>(sv, p[i], lm);
                extract_apply8<8>(sv, p[i], lm);
            }
        } else {            // chunk A factored (or being factored now): high half only
#pragma unroll
            for (int i = 0; i < 8; ++i) {
                const float2 la = colv[par][i][l];
                extract_apply8<8>(sv, p[i], (v2f){la.x, la.y});
            }
        }

        if (rd == w - 1)    // factor chunk A (group w); apply above already
            lookahead8<0>(sv, elim0, elim1, r0, r1, l, rd + 1,
                          colv[(rd + 1) & 1], keysF, pivsF, masks);
        if (rd == w + 7)    // factor chunk B (group w+8); retire after this
            lookahead8<8>(sv, elim0, elim1, r0, r1, l, rd + 1,
                          colv[(rd + 1) & 1], keysF, pivsF, masks);

        __syncthreads();
    }
    for (; rd < 15; ++rd) __syncthreads();   // retired waves: barrier-only

    // ---- log|det| = sum log|piv_k| over the write-once pivsF array ----
    float lg = 0.0f;
    if (t < NM) {
        lg = __logf(fabsf(pivsF[t]));
#pragma unroll
        for (int off = 32; off > 0; off >>= 1)
            lg += __shfl_xor(lg, off, 64);
        if ((t & 63) == 0) redf[t >> 6] = lg;
    }
    __syncthreads();
    if (t == 0) out[b] = redf[0] + redf[1];
}

extern "C" void kernel_launch(void* const* d_in, const int* in_sizes, int n_in,
                              void* d_out, int out_size, void* d_ws, size_t ws_size,
                              hipStream_t stream) {
    const float* rs = (const float*)d_in[0];
    const float* kp = (const float*)d_in[1];
    const float* cs = (const float*)d_in[2];
    const float* ss = (const float*)d_in[3];
    float* out = (float*)d_out;
    const int batch = in_sizes[0] / (NM * 3);  // 4096
    slater_logdet<<<dim3(batch), dim3(NT), 0, stream>>>(rs, kp, cs, ss, out);
}